// Round 6
// baseline (2090.993 us; speedup 1.0000x reference)
//
#include <hip/hip_runtime.h>
#include <cstdint>

typedef unsigned short u16;
typedef __bf16 bf16x8 __attribute__((ext_vector_type(8)));
typedef float f32x4 __attribute__((ext_vector_type(4)));

#define C_ 1024
#define T_ 2048
#define BT_ 4096
#define V_ 50257

enum { MODE_QKV = 0, MODE_SC = 1, MODE_PV = 2, MODE_LG = 3 };

__device__ __forceinline__ u16 f2bf(float f) {
  union { float f; unsigned u; } x; x.f = f;
  unsigned r = (x.u + 0x7fffu + ((x.u >> 16) & 1u)) >> 16;
  return (u16)r;
}

__device__ __forceinline__ void gld16(const u16* g, u16* l) {
  __builtin_amdgcn_global_load_lds(
      (const __attribute__((address_space(1))) void*)g,
      (__attribute__((address_space(3))) void*)l, 16, 0, 0);
}

// Generic B^T-layout bf16 MFMA GEMM: out[m,n] = sum_k A[m,k]*B[n,k]
// 128x128 tile, BK=32, 256 threads (4 waves, 2x2), m97 structure.
template <int MODE>
__global__ __launch_bounds__(256) void gemm_bt(
    const u16* __restrict__ A, const u16* __restrict__ B0,
    const u16* __restrict__ B1, const u16* __restrict__ B2,
    void* __restrict__ o0, void* __restrict__ o1, void* __restrict__ o2,
    const float* __restrict__ bias, int lda, int ldb, int K, int N,
    long sAz, long sBz) {
  const int tid = threadIdx.x;
  const int wid = tid >> 6;
  const int lane = tid & 63;
  const int z = blockIdx.z;
  const int n0 = blockIdx.x * 128;
  const int m0 = blockIdx.y * 128;

  // causal skip: whole score tile above the diagonal
  if (MODE == MODE_SC && n0 > m0 + 127) return;

  const u16* Bp = B0;
  if (MODE == MODE_QKV) Bp = (z == 0) ? B0 : ((z == 1) ? B1 : B2);
  const u16* Ap = A + (size_t)z * sAz;
  Bp += (size_t)z * sBz;

  __shared__ __align__(16) u16 As[128 * 32];
  __shared__ __align__(16) u16 Bs[128 * 32];

  const int arow = tid >> 2;          // 0..63
  const int acol = (tid & 3) * 8;     // 0,8,16,24

  const u16* Ag0 = Ap + (size_t)(m0 + arow) * lda + acol;
  const u16* Ag1 = Ag0 + (size_t)64 * lda;
  int br0 = n0 + arow, br1 = n0 + 64 + arow;
  if (MODE == MODE_LG) { br0 = min(br0, N - 1); br1 = min(br1, N - 1); }
  const u16* Bg0 = Bp + (size_t)br0 * ldb + acol;
  const u16* Bg1 = Bp + (size_t)br1 * ldb + acol;

  u16* AsW = As + wid * 512;  // wave-uniform LDS base (lane*16B implicit)
  u16* BsW = Bs + wid * 512;

  const int wr = wid >> 1, wc = wid & 1;
  const int fr = lane & 15, fg = lane >> 4;

  f32x4 acc[4][4];
  f32x4 zero = {0.f, 0.f, 0.f, 0.f};
#pragma unroll
  for (int m = 0; m < 4; ++m)
#pragma unroll
    for (int n = 0; n < 4; ++n) acc[m][n] = zero;

  const int Kend = (MODE == MODE_PV) ? (m0 + 128) : K;  // causal K truncation

  for (int k0 = 0; k0 < Kend; k0 += 32) {
    __syncthreads();
    gld16(Ag0 + k0, AsW);
    gld16(Ag1 + k0, AsW + 64 * 32);
    gld16(Bg0 + k0, BsW);
    gld16(Bg1 + k0, BsW + 64 * 32);
    __syncthreads();

    bf16x8 a[4], b[4];
#pragma unroll
    for (int m = 0; m < 4; ++m)
      a[m] = *(const bf16x8*)&As[(wr * 64 + m * 16 + fr) * 32 + fg * 8];
#pragma unroll
    for (int n = 0; n < 4; ++n)
      b[n] = *(const bf16x8*)&Bs[(wc * 64 + n * 16 + fr) * 32 + fg * 8];
#pragma unroll
    for (int m = 0; m < 4; ++m)
#pragma unroll
      for (int n = 0; n < 4; ++n)
        acc[m][n] =
            __builtin_amdgcn_mfma_f32_16x16x32_bf16(a[m], b[n], acc[m][n], 0, 0, 0);
  }

  // epilogue; C/D layout: col = lane&15, row = (lane>>4)*4 + reg  [m89/m91]
#pragma unroll
  for (int m = 0; m < 4; ++m) {
    const int row = m0 + wr * 64 + m * 16 + fg * 4;
#pragma unroll
    for (int n = 0; n < 4; ++n) {
      const int col = n0 + wc * 64 + n * 16 + fr;
      f32x4 v = acc[m][n];
      if (MODE == MODE_QKV) {
        if (z < 2) {
          u16* o = (u16*)((z == 0) ? o0 : o1);
#pragma unroll
          for (int j = 0; j < 4; ++j)
            o[(size_t)(row + j) * C_ + col] = f2bf(v[j]);
        } else {  // write v transposed: vT[c][t]
          u16* o = (u16*)o2;
#pragma unroll
          for (int j = 0; j < 4; ++j)
            o[(size_t)col * BT_ + (row + j)] = f2bf(v[j]);
        }
      } else if (MODE == MODE_SC) {
        float* o = (float*)o0 + (size_t)z * T_ * T_;
#pragma unroll
        for (int j = 0; j < 4; ++j)
          o[(size_t)(row + j) * T_ + col] = v[j];
      } else if (MODE == MODE_PV) {
        float* x = (float*)o0;
        u16* xb = (u16*)o1;
        const int rg = z * T_ + row;
#pragma unroll
        for (int j = 0; j < 4; ++j) {
          size_t ix = (size_t)(rg + j) * C_ + col;
          float nv = x[ix] + v[j];
          x[ix] = nv;
          xb[ix] = f2bf(nv);
        }
      } else {  // MODE_LG
        if (col < N) {
          float* o = (float*)o0;
          float bb = bias[col];
#pragma unroll
          for (int j = 0; j < 4; ++j)
            o[(size_t)(row + j) * (size_t)N + col] = v[j] + bb;
        }
      }
    }
  }
}

// one block per row; scale + causal mask + softmax; writes bf16 in place
__global__ __launch_bounds__(256) void softmax_causal(float* __restrict__ scores) {
  const int r = blockIdx.x;  // 0..4095
  const int b = r >> 11;
  const int i = r & (T_ - 1);
  float* srow = scores + (size_t)b * T_ * T_ + (size_t)i * T_;
  u16* orow = (u16*)srow;
  const int tid = threadIdx.x;
  __shared__ float red[4];

  float v[8];
  float mx = -1e30f;
#pragma unroll
  for (int s = 0; s < 8; ++s) {
    int j = tid + s * 256;
    float x = (j <= i) ? srow[j] * 0.03125f : -1e30f;
    v[s] = x;
    mx = fmaxf(mx, x);
  }
#pragma unroll
  for (int o = 32; o >= 1; o >>= 1) mx = fmaxf(mx, __shfl_xor(mx, o));
  if ((tid & 63) == 0) red[tid >> 6] = mx;
  __syncthreads();
  mx = fmaxf(fmaxf(red[0], red[1]), fmaxf(red[2], red[3]));
  __syncthreads();

  float sum = 0.f;
#pragma unroll
  for (int s = 0; s < 8; ++s) {
    int j = tid + s * 256;
    float e = (j <= i) ? __expf(v[s] - mx) : 0.f;
    v[s] = e;
    sum += e;
  }
#pragma unroll
  for (int o = 32; o >= 1; o >>= 1) sum += __shfl_xor(sum, o);
  if ((tid & 63) == 0) red[tid >> 6] = sum;
  __syncthreads();
  sum = red[0] + red[1] + red[2] + red[3];
  const float inv = 1.0f / sum;
#pragma unroll
  for (int s = 0; s < 8; ++s) {
    int j = tid + s * 256;
    orow[j] = f2bf(v[s] * inv);
  }
}

__global__ __launch_bounds__(256) void embed_k(
    const int* __restrict__ idx, const float* __restrict__ wemb,
    const float* __restrict__ wpos, float* __restrict__ x, u16* __restrict__ xb) {
  const int r = blockIdx.x;
  const int t = r & (T_ - 1);
  const int tok = idx[r];
  const int c = threadIdx.x * 4;
  const float4 e = *(const float4*)&wemb[(size_t)tok * C_ + c];
  const float4 p = *(const float4*)&wpos[(size_t)t * C_ + c];
  float4 s;
  s.x = e.x + p.x; s.y = e.y + p.y; s.z = e.z + p.z; s.w = e.w + p.w;
  *(float4*)&x[(size_t)r * C_ + c] = s;
  ushort4 h = make_ushort4(f2bf(s.x), f2bf(s.y), f2bf(s.z), f2bf(s.w));
  *(ushort4*)&xb[(size_t)r * C_ + c] = h;
}

__global__ __launch_bounds__(256) void cvt_k(const float* __restrict__ src,
                                             u16* __restrict__ dst, int n4) {
  const float4* s4 = (const float4*)src;
  ushort4* d4 = (ushort4*)dst;
  for (int i = blockIdx.x * 256 + threadIdx.x; i < n4; i += gridDim.x * 256) {
    float4 f = s4[i];
    d4[i] = make_ushort4(f2bf(f.x), f2bf(f.y), f2bf(f.z), f2bf(f.w));
  }
}

extern "C" void kernel_launch(void* const* d_in, const int* in_sizes, int n_in,
                              void* d_out, int out_size, void* d_ws, size_t ws_size,
                              hipStream_t stream) {
  const int* idx = (const int*)d_in[0];
  const float* wemb = (const float*)d_in[1];
  const float* wpos = (const float*)d_in[2];
  const float* wq = (const float*)d_in[3];
  const float* wk = (const float*)d_in[4];
  const float* wv = (const float*)d_in[5];
  const float* wout = (const float*)d_in[6];
  const float* bout = (const float*)d_in[7];
  float* out = (float*)d_out;
  char* ws = (char*)d_ws;

  const size_t CC = (size_t)C_ * C_;
  // workspace layout (MiB offsets), total ~197 MiB
  u16* xb = (u16*)(ws);                              // 8 MiB  [BT,C] bf16
  float* x = (float*)(ws + (size_t)(8) * 1048576);   // 16 MiB [BT,C] f32
  u16* q = (u16*)(ws + (size_t)(24) * 1048576);      // 8 MiB
  u16* k = (u16*)(ws + (size_t)(32) * 1048576);      // 8 MiB
  u16* vT = (u16*)(ws + (size_t)(40) * 1048576);     // 8 MiB  [C][BT]
  u16* wqb = (u16*)(ws + (size_t)(48) * 1048576);    // 6 MiB  [3][C][C]
  u16* wkb = (u16*)(ws + (size_t)(54) * 1048576);    // 6 MiB
  u16* wvb = (u16*)(ws + (size_t)(60) * 1048576);    // 6 MiB
  u16* wob = (u16*)(ws + (size_t)(66) * 1048576);    // 98.2 MiB [V][C]
  float* sc = (float*)(ws + (size_t)(165) * 1048576);// 32 MiB [B][T][T]

  cvt_k<<<1024, 256, 0, stream>>>(wq, wqb, (int)(3 * CC / 4));
  cvt_k<<<1024, 256, 0, stream>>>(wk, wkb, (int)(3 * CC / 4));
  cvt_k<<<1024, 256, 0, stream>>>(wv, wvb, (int)(3 * CC / 4));
  cvt_k<<<2048, 256, 0, stream>>>(wout, wob, (int)((size_t)V_ * C_ / 4));
  embed_k<<<BT_, 256, 0, stream>>>(idx, wemb, wpos, x, xb);

  for (int l = 0; l < 3; ++l) {
    gemm_bt<MODE_QKV><<<dim3(8, 32, 3), 256, 0, stream>>>(
        xb, wqb + l * CC, wkb + l * CC, wvb + l * CC, q, k, vT, nullptr,
        C_, C_, C_, C_, 0L, 0L);
    gemm_bt<MODE_SC><<<dim3(16, 16, 2), 256, 0, stream>>>(
        q, k, nullptr, nullptr, sc, nullptr, nullptr, nullptr,
        C_, C_, C_, T_, (long)T_ * C_, (long)T_ * C_);
    softmax_causal<<<BT_, 256, 0, stream>>>(sc);
    gemm_bt<MODE_PV><<<dim3(8, 16, 2), 256, 0, stream>>>(
        (const u16*)sc, vT, nullptr, nullptr, x, xb, nullptr, nullptr,
        2 * T_, BT_, T_, C_, (long)T_ * T_ * 2, (long)T_);
  }

  gemm_bt<MODE_LG><<<dim3(393, 32, 1), 256, 0, stream>>>(
      xb, wob, nullptr, nullptr, out, nullptr, nullptr, bout,
      C_, C_, C_, V_, 0L, 0L);
}